// Round 8
// baseline (154.508 us; speedup 1.0000x reference)
//
#include <hip/hip_runtime.h>
#include <cstdint>
#include <cstddef>

typedef __bf16 bf16;
typedef __bf16 bf16x8 __attribute__((ext_vector_type(8)));
typedef __bf16 bf16x4 __attribute__((ext_vector_type(4)));
typedef float  f32x4  __attribute__((ext_vector_type(4)));

#define MFMA16(a, b, c) __builtin_amdgcn_mfma_f32_16x16x32_bf16(a, b, c, 0, 0, 0)

// async global->LDS, 16B per lane, dest = wave-uniform base + lane*16
__device__ __forceinline__ void gl2lds16(const bf16* g, bf16* l) {
  __builtin_amdgcn_global_load_lds(
      (const __attribute__((address_space(1))) void*)g,
      (__attribute__((address_space(3))) void*)l, 16, 0, 0);
}

// ---------------------------------------------------------------------------
// prep: f32 -> bf16 casts (x, W_in, W_out) + q_cls passthrough copy
// ---------------------------------------------------------------------------
__device__ __forceinline__ void cvt4(const float* __restrict__ s, bf16* __restrict__ d) {
  f32x4 v = *(const f32x4*)s;
  bf16x4 o;
  o[0] = (bf16)v[0]; o[1] = (bf16)v[1]; o[2] = (bf16)v[2]; o[3] = (bf16)v[3];
  *(bf16x4*)d = o;
}

__global__ __launch_bounds__(256) void prep_kernel(
    const float* __restrict__ q, const float* __restrict__ win,
    const float* __restrict__ wout, float* __restrict__ out0,
    bf16* __restrict__ xb, bf16* __restrict__ wqb, bf16* __restrict__ wob) {
  long u = (long)blockIdx.x * 256 + threadIdx.x;
  const long NX4 = 1605632, NWQ4 = 196608, NWO4 = 65536, NQC4 = 1024;
  if (u < NX4) { cvt4(q + 4096 + u * 4, xb + u * 4); return; }
  u -= NX4;
  if (u < NWQ4) { cvt4(win + u * 4, wqb + u * 4); return; }
  u -= NWQ4;
  if (u < NWO4) { cvt4(wout + u * 4, wob + u * 4); return; }
  u -= NWO4;
  if (u < NQC4) { *(f32x4*)(out0 + u * 4) = *(const f32x4*)(q + u * 4); }
}

// ---------------------------------------------------------------------------
// GEMM: C[m][n] = sum_k A[m][k] * B[n][k] + bias[n]
// 128x128 tile, BK=32, 4 waves, global_load_lds staging, XCD swizzle.
// OUTF32 path (final output, never re-read) uses non-temporal stores.
// ---------------------------------------------------------------------------
template <bool OUTF32>
__global__ __launch_bounds__(256) void gemm_bt(
    const bf16* __restrict__ A, const bf16* __restrict__ Bm,
    const float* __restrict__ bias, bf16* __restrict__ Cb,
    float* __restrict__ Cf, int N, int K, long coff) {
  __shared__ bf16 As[128 * 32];
  __shared__ bf16 Bs[128 * 32];
  const int tid = threadIdx.x;
  const int wid = tid >> 6, lane = tid & 63;
  const int lr = lane & 15, lg = lane >> 4;

  const int nwg = gridDim.x * gridDim.y;        // multiple of 8
  const int orig = blockIdx.y * gridDim.x + blockIdx.x;
  const int cpx = nwg >> 3;
  const int swz = (orig & 7) * cpx + (orig >> 3);
  const int m0 = (swz / gridDim.x) * 128;
  const int n0 = (swz % gridDim.x) * 128;

  const int wr = wid >> 1, wc = wid & 1;
  const int srow = lane >> 2;                   // 0..15
  const int scol = (lane & 3) * 8;              // 0,8,16,24

  f32x4 acc[4][4] = {};

  for (int kt = 0; kt < K; kt += 32) {
    __syncthreads();
#pragma unroll
    for (int j = 0; j < 2; ++j) {
      int r0 = wid * 32 + j * 16;
      gl2lds16(A + (size_t)(m0 + r0 + srow) * K + kt + scol, As + r0 * 32);
      gl2lds16(Bm + (size_t)(n0 + r0 + srow) * K + kt + scol, Bs + r0 * 32);
    }
    __syncthreads();

    bf16x8 af[4], bfr[4];
#pragma unroll
    for (int m = 0; m < 4; ++m)
      af[m] = *(const bf16x8*)(As + (wr * 64 + m * 16 + lr) * 32 + lg * 8);
#pragma unroll
    for (int n = 0; n < 4; ++n)
      bfr[n] = *(const bf16x8*)(Bs + (wc * 64 + n * 16 + lr) * 32 + lg * 8);
#pragma unroll
    for (int m = 0; m < 4; ++m)
#pragma unroll
      for (int n = 0; n < 4; ++n)
        acc[m][n] = MFMA16(af[m], bfr[n], acc[m][n]);
  }

#pragma unroll
  for (int m = 0; m < 4; ++m) {
    int row = m0 + wr * 64 + m * 16 + lg * 4;
#pragma unroll
    for (int n = 0; n < 4; ++n) {
      int col = n0 + wc * 64 + n * 16 + lr;
      float bv = bias[col];
#pragma unroll
      for (int i = 0; i < 4; ++i) {
        float v = acc[m][n][i] + bv;
        if (OUTF32)
          __builtin_nontemporal_store(v, Cf + coff + (size_t)(row + i) * N + col);
        else
          Cb[(size_t)(row + i) * N + col] = (bf16)v;
      }
    }
  }
}

// ---------------------------------------------------------------------------
// Spatial attention, swapped-QK^T. One block per (h,bb,ti), 8 waves,
// 2 blocks/CU (62 KB LDS). attn written with NON-TEMPORAL f32x4 stores.
// V transposed with wave-per-column-chunk mapping (conflict-free banking).
// BOTH staging loops carry the pp<224 guard (r7 bug: dropped guard -> OOB
// LDS writes zeroed V data -> absmax 0.26).
// ---------------------------------------------------------------------------
__global__ __launch_bounds__(512) void spatial_attn(
    const bf16* __restrict__ qkv, float* __restrict__ attn_out,
    bf16* __restrict__ outs) {
  __shared__ bf16 Kl[224][72];        // [k-row][d]  stride 144B
  __shared__ bf16 Vt[64][232];        // [d][k-row]  stride 464B

  const int tid = threadIdx.x;
  const int wid = tid >> 6, lane = tid & 63;
  const int lr = lane & 15, lg = lane >> 4;
  const int batch = blockIdx.x;            // (h*8 + bb)*8 + ti
  const int ti = batch & 7;
  const int bb = (batch >> 3) & 7;
  const int h = batch >> 6;

  // ---- stage K (row-major, b128 writes), zero-pad rows >=196
  {
    const int p = (tid >> 3);                // 0..63
    const int c = (tid & 7) * 8;
    bf16 zz = (bf16)0.f;
    for (int r0 = 0; r0 < 224; r0 += 64) {
      int pp = r0 + p;
      bf16x8 kv = {zz, zz, zz, zz, zz, zz, zz, zz};
      if (pp < 196) {
        size_t ro = ((size_t)(ti * 196 + pp) * 8 + bb) * 1536 + h * 64 + c;
        kv = *(const bf16x8*)(qkv + ro + 512);
      }
      if (pp < 224) *(bf16x8*)&Kl[pp][c] = kv;
    }
  }
  // ---- stage V transposed: wave w owns cols c=w*8..w*8+7, lane = row
  // per store instr pp spans 64 rows -> 32 banks, 2 lanes/bank (free)
  {
    const int c = wid * 8;
    bf16 zz = (bf16)0.f;
    for (int r0 = 0; r0 < 224; r0 += 64) {
      int pp = r0 + lane;
      bf16x8 vv = {zz, zz, zz, zz, zz, zz, zz, zz};
      if (pp < 196) {
        size_t ro = ((size_t)(ti * 196 + pp) * 8 + bb) * 1536 + h * 64 + c;
        vv = *(const bf16x8*)(qkv + ro + 1024);
      }
      if (pp < 224) {
#pragma unroll
        for (int j = 0; j < 8; ++j) Vt[c + j][pp] = vv[j];
      }
    }
  }
  __syncthreads();

  // ---- per-wave 16-row Q tiles; 13 tiles cover 196
  for (int qt = wid; qt < 13; qt += 8) {
    const int q = qt * 16 + lr;              // this lane's q-row
    bf16x8 aq[2];
    {
      int row = q > 195 ? 195 : q;           // clamp; discarded on store
      size_t ro = ((size_t)(ti * 196 + row) * 8 + bb) * 1536 + h * 64;
#pragma unroll
      for (int kk = 0; kk < 2; ++kk)
        aq[kk] = *(const bf16x8*)(qkv + ro + kk * 32 + lg * 8);
    }

    // S^T = K Q^T : lane -> q=lr, k = nn*16 + lg*4 + i
    f32x4 s[14] = {};
#pragma unroll
    for (int nn = 0; nn < 14; ++nn) {
      bf16x8 bk0 = *(const bf16x8*)&Kl[nn * 16 + lr][lg * 8];
      bf16x8 bk1 = *(const bf16x8*)&Kl[nn * 16 + lr][32 + lg * 8];
      s[nn] = MFMA16(bk0, aq[0], s[nn]);     // swapped operands
      s[nn] = MFMA16(bk1, aq[1], s[nn]);
    }

    // scale + mask pad cols (vector-uniform: 196 % 4 == 0)
#pragma unroll
    for (int nn = 0; nn < 14; ++nn) {
      bool pad = (nn * 16 + lg * 4 >= 196);
#pragma unroll
      for (int i = 0; i < 4; ++i)
        s[nn][i] = pad ? -1e30f : s[nn][i] * 0.125f;
    }

    // softmax over k: local 56 + 4-lane group reduce (lanes lr,+16,+32,+48)
    float v = -1e30f;
#pragma unroll
    for (int nn = 0; nn < 14; ++nn)
#pragma unroll
      for (int i = 0; i < 4; ++i) v = fmaxf(v, s[nn][i]);
    v = fmaxf(v, __shfl_xor(v, 16));
    v = fmaxf(v, __shfl_xor(v, 32));
    float sum = 0.f;
#pragma unroll
    for (int nn = 0; nn < 14; ++nn)
#pragma unroll
      for (int i = 0; i < 4; ++i) {
        float e = __expf(s[nn][i] - v);
        s[nn][i] = e;
        sum += e;
      }
    sum += __shfl_xor(sum, 16);
    sum += __shfl_xor(sum, 32);
    const float rinv = 1.f / sum;

    // fused epilogue: per kb consume s[2kb],s[2kb+1]:
    // normalize -> attn NT-store (f32x4) -> pack bf16 -> shuffle -> PV
    const int low = lr + 32 * (lg & 1);
    const int high = low + 16;
    const bool hiN = (lg >> 1) != 0;
    f32x4 o[4] = {};
#pragma unroll
    for (int kb = 0; kb < 7; ++kb) {
      uint32_t px[2], py[2];
#pragma unroll
      for (int t = 0; t < 2; ++t) {
        const int nn = 2 * kb + t;
        f32x4 sv;
#pragma unroll
        for (int i = 0; i < 4; ++i) sv[i] = s[nn][i] * rinv;
        int kbase = nn * 16 + lg * 4;
        if (q < 196 && kbase < 196)
          __builtin_nontemporal_store(
              sv, (f32x4*)(attn_out + (size_t)batch * 38416 +
                           (size_t)q * 196 + kbase));
        union { bf16x4 h; uint2 u; } pk;
        pk.h[0] = (bf16)sv[0]; pk.h[1] = (bf16)sv[1];
        pk.h[2] = (bf16)sv[2]; pk.h[3] = (bf16)sv[3];
        px[t] = pk.u.x; py[t] = pk.u.y;
      }
      uint32_t a0x = __shfl((int)px[0], low);
      uint32_t a0y = __shfl((int)py[0], low);
      uint32_t a1x = __shfl((int)px[1], low);
      uint32_t a1y = __shfl((int)py[1], low);
      uint32_t b0x = __shfl((int)px[0], high);
      uint32_t b0y = __shfl((int)py[0], high);
      uint32_t b1x = __shfl((int)px[1], high);
      uint32_t b1y = __shfl((int)py[1], high);
      union { uint32_t u[4]; bf16x8 h; } pa;
      pa.u[0] = hiN ? a1x : a0x;
      pa.u[1] = hiN ? a1y : a0y;
      pa.u[2] = hiN ? b1x : b0x;
      pa.u[3] = hiN ? b1y : b0y;
#pragma unroll
      for (int nd = 0; nd < 4; ++nd) {
        bf16x8 vb = *(const bf16x8*)&Vt[nd * 16 + lr][kb * 32 + lg * 8];
        o[nd] = MFMA16(pa.h, vb, o[nd]);
      }
    }

    // write out_s in v_t layout [h][bb][p][ti][d]; o: row=q'=lg*4+i, col=d
#pragma unroll
    for (int i = 0; i < 4; ++i) {
      int p = qt * 16 + lg * 4 + i;
      if (p < 196) {
#pragma unroll
        for (int nd = 0; nd < 4; ++nd) {
          int d = nd * 16 + lr;
          outs[(((size_t)((h * 8 + bb) * 196 + p)) * 8 + ti) * 64 + d] =
              (bf16)o[nd][i];
        }
      }
    }
  }
}

// ---------------------------------------------------------------------------
// Temporal attention: 1 wave per (h, bb, p) batch; t=8, dh=64.
// ---------------------------------------------------------------------------
__global__ __launch_bounds__(256) void temporal_attn(
    const bf16* __restrict__ qkv, const bf16* __restrict__ outs,
    bf16* __restrict__ outt) {
  __shared__ bf16 Ql[4][8][72];
  __shared__ bf16 Kc[4][8][72];
  __shared__ bf16 Vl[4][8][64];
  __shared__ float Ps[4][8][8];

  const int tid = threadIdx.x, wid = tid >> 6, lane = tid & 63;
  const int batch = blockIdx.x * 4 + wid;  // (h*8+bb)*196 + p
  const int p = batch % 196;
  const int hb = batch / 196;
  const int bb = hb & 7, h = hb >> 3;

  const int ri = lane >> 3;        // t-row 0..7
  const int c8 = lane & 7;         // 8-elem chunk of d
  {
    size_t ro = ((size_t)(ri * 196 + p) * 8 + bb) * 1536 + h * 64 + c8 * 8;
    *(bf16x8*)&Ql[wid][ri][c8 * 8] = *(const bf16x8*)(qkv + ro);
    *(bf16x8*)&Kc[wid][ri][c8 * 8] = *(const bf16x8*)(qkv + ro + 512);
    *(bf16x8*)&Vl[wid][ri][c8 * 8] =
        *(const bf16x8*)(outs + ((size_t)batch * 8 + ri) * 64 + c8 * 8);
  }
  __syncthreads();

  float s = 0.f;
#pragma unroll
  for (int d = 0; d < 64; d += 8) {
    bf16x8 qv = *(const bf16x8*)&Ql[wid][ri][d];
    bf16x8 kv = *(const bf16x8*)&Kc[wid][c8][d];
#pragma unroll
    for (int e = 0; e < 8; ++e) s += (float)qv[e] * (float)kv[e];
  }
  s *= 0.125f;
  float mxv = s;
#pragma unroll
  for (int d2 = 1; d2 < 8; d2 <<= 1) mxv = fmaxf(mxv, __shfl_xor(mxv, d2));
  float e = __expf(s - mxv);
  float sum = e;
#pragma unroll
  for (int d2 = 1; d2 < 8; d2 <<= 1) sum += __shfl_xor(sum, d2);
  Ps[wid][ri][c8] = e / sum;
  __syncthreads();

  const int d = lane;
#pragma unroll
  for (int ii = 0; ii < 8; ++ii) {
    float o = 0.f;
#pragma unroll
    for (int j = 0; j < 8; ++j) o += Ps[wid][ii][j] * (float)Vl[wid][j][d];
    outt[((size_t)(ii * 196 + p) * 8 + bb) * 512 + h * 64 + d] = (bf16)o;
  }
}

// ---------------------------------------------------------------------------
extern "C" void kernel_launch(void* const* d_in, const int* in_sizes, int n_in,
                              void* d_out, int out_size, void* d_ws,
                              size_t ws_size, hipStream_t stream) {
  (void)in_sizes; (void)n_in; (void)out_size; (void)ws_size;
  const float* q    = (const float*)d_in[0];
  const float* win  = (const float*)d_in[3];
  const float* bin  = (const float*)d_in[4];
  const float* wout = (const float*)d_in[5];
  const float* bout = (const float*)d_in[6];
  float* out0 = (float*)d_out;
  float* attn = out0 + 6426624L;   // 1569*8*512

  // ws layout (64,749,568 bytes total):
  bf16* qkv  = (bf16*)d_ws;                 // 12544*1536
  bf16* outs = qkv + 19267584L;             // 8*8*196*8*64
  bf16* outt = outs + 6422528L;             // 12544*512
  bf16* wob  = outt + 6422528L;             // 512*512

  // gemm1-only scratch inside attn region of d_out (rewritten by spatial):
  bf16* xb  = (bf16*)attn;                  // 12544*512
  bf16* wqb = xb + 6422528L;                // 1536*512

  prep_kernel<<<7300, 256, 0, stream>>>(q, win, wout, out0, xb, wqb, wob);
  gemm_bt<false><<<dim3(12, 98), 256, 0, stream>>>(xb, wqb, bin, qkv, nullptr,
                                                   1536, 512, 0);
  spatial_attn<<<512, 512, 0, stream>>>(qkv, attn, outs);
  temporal_attn<<<3136, 256, 0, stream>>>(qkv, outs, outt);
  gemm_bt<true><<<dim3(4, 98), 256, 0, stream>>>(outt, wob, bout, nullptr,
                                                 out0, 512, 512, 4096);
}

// Round 9
// 137.823 us; speedup vs baseline: 1.1211x; 1.1211x over previous
//
#include <hip/hip_runtime.h>
#include <cstdint>
#include <cstddef>

typedef __bf16 bf16;
typedef __bf16 bf16x8 __attribute__((ext_vector_type(8)));
typedef __bf16 bf16x4 __attribute__((ext_vector_type(4)));
typedef float  f32x4  __attribute__((ext_vector_type(4)));

#define MFMA16(a, b, c) __builtin_amdgcn_mfma_f32_16x16x32_bf16(a, b, c, 0, 0, 0)

// async global->LDS, 16B per lane, dest = wave-uniform base + lane*16
__device__ __forceinline__ void gl2lds16(const bf16* g, bf16* l) {
  __builtin_amdgcn_global_load_lds(
      (const __attribute__((address_space(1))) void*)g,
      (__attribute__((address_space(3))) void*)l, 16, 0, 0);
}

// ---------------------------------------------------------------------------
// prep: f32 -> bf16 casts (x, W_in, W_out) + q_cls passthrough copy
// ---------------------------------------------------------------------------
__device__ __forceinline__ void cvt4(const float* __restrict__ s, bf16* __restrict__ d) {
  f32x4 v = *(const f32x4*)s;
  bf16x4 o;
  o[0] = (bf16)v[0]; o[1] = (bf16)v[1]; o[2] = (bf16)v[2]; o[3] = (bf16)v[3];
  *(bf16x4*)d = o;
}

__global__ __launch_bounds__(256) void prep_kernel(
    const float* __restrict__ q, const float* __restrict__ win,
    const float* __restrict__ wout, float* __restrict__ out0,
    bf16* __restrict__ xb, bf16* __restrict__ wqb, bf16* __restrict__ wob) {
  long u = (long)blockIdx.x * 256 + threadIdx.x;
  const long NX4 = 1605632, NWQ4 = 196608, NWO4 = 65536, NQC4 = 1024;
  if (u < NX4) { cvt4(q + 4096 + u * 4, xb + u * 4); return; }
  u -= NX4;
  if (u < NWQ4) { cvt4(win + u * 4, wqb + u * 4); return; }
  u -= NWQ4;
  if (u < NWO4) { cvt4(wout + u * 4, wob + u * 4); return; }
  u -= NWO4;
  if (u < NQC4) { *(f32x4*)(out0 + u * 4) = *(const f32x4*)(q + u * 4); }
}

// ---------------------------------------------------------------------------
// GEMM: C[m][n] = sum_k A[m][k] * B[n][k] + bias[n]
// 128x128 tile, BK=32, 4 waves, global_load_lds staging, XCD swizzle.
// OUTF32 path (final output, never re-read) keeps non-temporal stores
// (measured ~neutral; contiguous full-row output).
// ---------------------------------------------------------------------------
template <bool OUTF32>
__global__ __launch_bounds__(256) void gemm_bt(
    const bf16* __restrict__ A, const bf16* __restrict__ Bm,
    const float* __restrict__ bias, bf16* __restrict__ Cb,
    float* __restrict__ Cf, int N, int K, long coff) {
  __shared__ bf16 As[128 * 32];
  __shared__ bf16 Bs[128 * 32];
  const int tid = threadIdx.x;
  const int wid = tid >> 6, lane = tid & 63;
  const int lr = lane & 15, lg = lane >> 4;

  const int nwg = gridDim.x * gridDim.y;        // multiple of 8
  const int orig = blockIdx.y * gridDim.x + blockIdx.x;
  const int cpx = nwg >> 3;
  const int swz = (orig & 7) * cpx + (orig >> 3);
  const int m0 = (swz / gridDim.x) * 128;
  const int n0 = (swz % gridDim.x) * 128;

  const int wr = wid >> 1, wc = wid & 1;
  const int srow = lane >> 2;                   // 0..15
  const int scol = (lane & 3) * 8;              // 0,8,16,24

  f32x4 acc[4][4] = {};

  for (int kt = 0; kt < K; kt += 32) {
    __syncthreads();
#pragma unroll
    for (int j = 0; j < 2; ++j) {
      int r0 = wid * 32 + j * 16;
      gl2lds16(A + (size_t)(m0 + r0 + srow) * K + kt + scol, As + r0 * 32);
      gl2lds16(Bm + (size_t)(n0 + r0 + srow) * K + kt + scol, Bs + r0 * 32);
    }
    __syncthreads();

    bf16x8 af[4], bfr[4];
#pragma unroll
    for (int m = 0; m < 4; ++m)
      af[m] = *(const bf16x8*)(As + (wr * 64 + m * 16 + lr) * 32 + lg * 8);
#pragma unroll
    for (int n = 0; n < 4; ++n)
      bfr[n] = *(const bf16x8*)(Bs + (wc * 64 + n * 16 + lr) * 32 + lg * 8);
#pragma unroll
    for (int m = 0; m < 4; ++m)
#pragma unroll
      for (int n = 0; n < 4; ++n)
        acc[m][n] = MFMA16(af[m], bfr[n], acc[m][n]);
  }

#pragma unroll
  for (int m = 0; m < 4; ++m) {
    int row = m0 + wr * 64 + m * 16 + lg * 4;
#pragma unroll
    for (int n = 0; n < 4; ++n) {
      int col = n0 + wc * 64 + n * 16 + lr;
      float bv = bias[col];
#pragma unroll
      for (int i = 0; i < 4; ++i) {
        float v = acc[m][n][i] + bv;
        if (OUTF32)
          __builtin_nontemporal_store(v, Cf + coff + (size_t)(row + i) * N + col);
        else
          Cb[(size_t)(row + i) * N + col] = (bf16)v;
      }
    }
  }
}

// ---------------------------------------------------------------------------
// Spatial attention, swapped-QK^T. One block per (h,bb,ti), 8 waves.
// PLAIN f32x4 attn stores (NT measured +52MB write / +16us regression, r8).
// lds_pad forces 1 block/CU: at 2 blocks/CU the 154KB/block attn stream
// thrashes the per-CU L2 share -> partial lines evicted between the 64B
// t-store pairs -> write-allocate fetch (+48MB) + double write (+84MB).
// r3's 121KB-LDS design (1 block/CU) ran ~36us on the same store pattern.
// ---------------------------------------------------------------------------
__global__ __launch_bounds__(512) void spatial_attn(
    const bf16* __restrict__ qkv, float* __restrict__ attn_out,
    bf16* __restrict__ outs) {
  __shared__ bf16 Kl[224][72];        // [k-row][d]  stride 144B
  __shared__ bf16 Vt[64][232];        // [d][k-row]  stride 464B
  __shared__ bf16 lds_pad[12288];     // 24KB -> total 86KB -> 1 block/CU

  const int tid = threadIdx.x;
  const int wid = tid >> 6, lane = tid & 63;
  const int lr = lane & 15, lg = lane >> 4;
  const int batch = blockIdx.x;            // (h*8 + bb)*8 + ti
  const int ti = batch & 7;
  const int bb = (batch >> 3) & 7;
  const int h = batch >> 6;

  if (attn_out == nullptr) lds_pad[tid] = (bf16)0.f;  // never true; keeps pad

  // ---- stage K (row-major, b128 writes), zero-pad rows >=196
  {
    const int p = (tid >> 3);                // 0..63
    const int c = (tid & 7) * 8;
    bf16 zz = (bf16)0.f;
    for (int r0 = 0; r0 < 224; r0 += 64) {
      int pp = r0 + p;
      bf16x8 kv = {zz, zz, zz, zz, zz, zz, zz, zz};
      if (pp < 196) {
        size_t ro = ((size_t)(ti * 196 + pp) * 8 + bb) * 1536 + h * 64 + c;
        kv = *(const bf16x8*)(qkv + ro + 512);
      }
      if (pp < 224) *(bf16x8*)&Kl[pp][c] = kv;
    }
  }
  // ---- stage V transposed: wave w owns cols c=w*8..w*8+7, lane = row
  {
    const int c = wid * 8;
    bf16 zz = (bf16)0.f;
    for (int r0 = 0; r0 < 224; r0 += 64) {
      int pp = r0 + lane;
      bf16x8 vv = {zz, zz, zz, zz, zz, zz, zz, zz};
      if (pp < 196) {
        size_t ro = ((size_t)(ti * 196 + pp) * 8 + bb) * 1536 + h * 64 + c;
        vv = *(const bf16x8*)(qkv + ro + 1024);
      }
      if (pp < 224) {
#pragma unroll
        for (int j = 0; j < 8; ++j) Vt[c + j][pp] = vv[j];
      }
    }
  }
  __syncthreads();

  // ---- per-wave 16-row Q tiles; 13 tiles cover 196
  for (int qt = wid; qt < 13; qt += 8) {
    const int q = qt * 16 + lr;              // this lane's q-row
    bf16x8 aq[2];
    {
      int row = q > 195 ? 195 : q;           // clamp; discarded on store
      size_t ro = ((size_t)(ti * 196 + row) * 8 + bb) * 1536 + h * 64;
#pragma unroll
      for (int kk = 0; kk < 2; ++kk)
        aq[kk] = *(const bf16x8*)(qkv + ro + kk * 32 + lg * 8);
    }

    // S^T = K Q^T : lane -> q=lr, k = nn*16 + lg*4 + i
    f32x4 s[14] = {};
#pragma unroll
    for (int nn = 0; nn < 14; ++nn) {
      bf16x8 bk0 = *(const bf16x8*)&Kl[nn * 16 + lr][lg * 8];
      bf16x8 bk1 = *(const bf16x8*)&Kl[nn * 16 + lr][32 + lg * 8];
      s[nn] = MFMA16(bk0, aq[0], s[nn]);     // swapped operands
      s[nn] = MFMA16(bk1, aq[1], s[nn]);
    }

    // scale + mask pad cols (vector-uniform: 196 % 4 == 0)
#pragma unroll
    for (int nn = 0; nn < 14; ++nn) {
      bool pad = (nn * 16 + lg * 4 >= 196);
#pragma unroll
      for (int i = 0; i < 4; ++i)
        s[nn][i] = pad ? -1e30f : s[nn][i] * 0.125f;
    }

    // softmax over k: local 56 + 4-lane group reduce (lanes lr,+16,+32,+48)
    float v = -1e30f;
#pragma unroll
    for (int nn = 0; nn < 14; ++nn)
#pragma unroll
      for (int i = 0; i < 4; ++i) v = fmaxf(v, s[nn][i]);
    v = fmaxf(v, __shfl_xor(v, 16));
    v = fmaxf(v, __shfl_xor(v, 32));
    float sum = 0.f;
#pragma unroll
    for (int nn = 0; nn < 14; ++nn)
#pragma unroll
      for (int i = 0; i < 4; ++i) {
        float e = __expf(s[nn][i] - v);
        s[nn][i] = e;
        sum += e;
      }
    sum += __shfl_xor(sum, 16);
    sum += __shfl_xor(sum, 32);
    const float rinv = 1.f / sum;

    // fused epilogue: per kb consume s[2kb],s[2kb+1]:
    // normalize -> attn store (f32x4) -> pack bf16 -> shuffle -> PV
    const int low = lr + 32 * (lg & 1);
    const int high = low + 16;
    const bool hiN = (lg >> 1) != 0;
    f32x4 o[4] = {};
#pragma unroll
    for (int kb = 0; kb < 7; ++kb) {
      uint32_t px[2], py[2];
#pragma unroll
      for (int t = 0; t < 2; ++t) {
        const int nn = 2 * kb + t;
        f32x4 sv;
#pragma unroll
        for (int i = 0; i < 4; ++i) sv[i] = s[nn][i] * rinv;
        int kbase = nn * 16 + lg * 4;
        if (q < 196 && kbase < 196)
          *(f32x4*)(attn_out + (size_t)batch * 38416 + (size_t)q * 196 +
                    kbase) = sv;
        union { bf16x4 h; uint2 u; } pk;
        pk.h[0] = (bf16)sv[0]; pk.h[1] = (bf16)sv[1];
        pk.h[2] = (bf16)sv[2]; pk.h[3] = (bf16)sv[3];
        px[t] = pk.u.x; py[t] = pk.u.y;
      }
      uint32_t a0x = __shfl((int)px[0], low);
      uint32_t a0y = __shfl((int)py[0], low);
      uint32_t a1x = __shfl((int)px[1], low);
      uint32_t a1y = __shfl((int)py[1], low);
      uint32_t b0x = __shfl((int)px[0], high);
      uint32_t b0y = __shfl((int)py[0], high);
      uint32_t b1x = __shfl((int)px[1], high);
      uint32_t b1y = __shfl((int)py[1], high);
      union { uint32_t u[4]; bf16x8 h; } pa;
      pa.u[0] = hiN ? a1x : a0x;
      pa.u[1] = hiN ? a1y : a0y;
      pa.u[2] = hiN ? b1x : b0x;
      pa.u[3] = hiN ? b1y : b0y;
#pragma unroll
      for (int nd = 0; nd < 4; ++nd) {
        bf16x8 vb = *(const bf16x8*)&Vt[nd * 16 + lr][kb * 32 + lg * 8];
        o[nd] = MFMA16(pa.h, vb, o[nd]);
      }
    }

    // write out_s in v_t layout [h][bb][p][ti][d]; o: row=q'=lg*4+i, col=d
#pragma unroll
    for (int i = 0; i < 4; ++i) {
      int p = qt * 16 + lg * 4 + i;
      if (p < 196) {
#pragma unroll
        for (int nd = 0; nd < 4; ++nd) {
          int d = nd * 16 + lr;
          outs[(((size_t)((h * 8 + bb) * 196 + p)) * 8 + ti) * 64 + d] =
              (bf16)o[nd][i];
        }
      }
    }
  }
}

// ---------------------------------------------------------------------------
// Temporal attention: 1 wave per (h, bb, p) batch; t=8, dh=64.
// ---------------------------------------------------------------------------
__global__ __launch_bounds__(256) void temporal_attn(
    const bf16* __restrict__ qkv, const bf16* __restrict__ outs,
    bf16* __restrict__ outt) {
  __shared__ bf16 Ql[4][8][72];
  __shared__ bf16 Kc[4][8][72];
  __shared__ bf16 Vl[4][8][64];
  __shared__ float Ps[4][8][8];

  const int tid = threadIdx.x, wid = tid >> 6, lane = tid & 63;
  const int batch = blockIdx.x * 4 + wid;  // (h*8+bb)*196 + p
  const int p = batch % 196;
  const int hb = batch / 196;
  const int bb = hb & 7, h = hb >> 3;

  const int ri = lane >> 3;        // t-row 0..7
  const int c8 = lane & 7;         // 8-elem chunk of d
  {
    size_t ro = ((size_t)(ri * 196 + p) * 8 + bb) * 1536 + h * 64 + c8 * 8;
    *(bf16x8*)&Ql[wid][ri][c8 * 8] = *(const bf16x8*)(qkv + ro);
    *(bf16x8*)&Kc[wid][ri][c8 * 8] = *(const bf16x8*)(qkv + ro + 512);
    *(bf16x8*)&Vl[wid][ri][c8 * 8] =
        *(const bf16x8*)(outs + ((size_t)batch * 8 + ri) * 64 + c8 * 8);
  }
  __syncthreads();

  float s = 0.f;
#pragma unroll
  for (int d = 0; d < 64; d += 8) {
    bf16x8 qv = *(const bf16x8*)&Ql[wid][ri][d];
    bf16x8 kv = *(const bf16x8*)&Kc[wid][c8][d];
#pragma unroll
    for (int e = 0; e < 8; ++e) s += (float)qv[e] * (float)kv[e];
  }
  s *= 0.125f;
  float mxv = s;
#pragma unroll
  for (int d2 = 1; d2 < 8; d2 <<= 1) mxv = fmaxf(mxv, __shfl_xor(mxv, d2));
  float e = __expf(s - mxv);
  float sum = e;
#pragma unroll
  for (int d2 = 1; d2 < 8; d2 <<= 1) sum += __shfl_xor(sum, d2);
  Ps[wid][ri][c8] = e / sum;
  __syncthreads();

  const int d = lane;
#pragma unroll
  for (int ii = 0; ii < 8; ++ii) {
    float o = 0.f;
#pragma unroll
    for (int j = 0; j < 8; ++j) o += Ps[wid][ii][j] * (float)Vl[wid][j][d];
    outt[((size_t)(ii * 196 + p) * 8 + bb) * 512 + h * 64 + d] = (bf16)o;
  }
}

// ---------------------------------------------------------------------------
extern "C" void kernel_launch(void* const* d_in, const int* in_sizes, int n_in,
                              void* d_out, int out_size, void* d_ws,
                              size_t ws_size, hipStream_t stream) {
  (void)in_sizes; (void)n_in; (void)out_size; (void)ws_size;
  const float* q    = (const float*)d_in[0];
  const float* win  = (const float*)d_in[3];
  const float* bin  = (const float*)d_in[4];
  const float* wout = (const float*)d_in[5];
  const float* bout = (const float*)d_in[6];
  float* out0 = (float*)d_out;
  float* attn = out0 + 6426624L;   // 1569*8*512

  // ws layout (64,749,568 bytes total):
  bf16* qkv  = (bf16*)d_ws;                 // 12544*1536
  bf16* outs = qkv + 19267584L;             // 8*8*196*8*64
  bf16* outt = outs + 6422528L;             // 12544*512
  bf16* wob  = outt + 6422528L;             // 512*512

  // gemm1-only scratch inside attn region of d_out (rewritten by spatial):
  bf16* xb  = (bf16*)attn;                  // 12544*512
  bf16* wqb = xb + 6422528L;                // 1536*512

  prep_kernel<<<7300, 256, 0, stream>>>(q, win, wout, out0, xb, wqb, wob);
  gemm_bt<false><<<dim3(12, 98), 256, 0, stream>>>(xb, wqb, bin, qkv, nullptr,
                                                   1536, 512, 0);
  spatial_attn<<<512, 512, 0, stream>>>(qkv, attn, outs);
  temporal_attn<<<3136, 256, 0, stream>>>(qkv, outs, outt);
  gemm_bt<true><<<dim3(4, 98), 256, 0, stream>>>(outt, wob, bout, nullptr,
                                                 out0, 512, 512, 4096);
}

// Round 10
// 129.725 us; speedup vs baseline: 1.1910x; 1.0624x over previous
//
#include <hip/hip_runtime.h>
#include <cstdint>
#include <cstddef>

typedef __bf16 bf16;
typedef __bf16 bf16x8 __attribute__((ext_vector_type(8)));
typedef __bf16 bf16x4 __attribute__((ext_vector_type(4)));
typedef float  f32x4  __attribute__((ext_vector_type(4)));

#define MFMA16(a, b, c) __builtin_amdgcn_mfma_f32_16x16x32_bf16(a, b, c, 0, 0, 0)

// async global->LDS, 16B per lane, dest = wave-uniform base + lane*16
__device__ __forceinline__ void gl2lds16(const bf16* g, bf16* l) {
  __builtin_amdgcn_global_load_lds(
      (const __attribute__((address_space(1))) void*)g,
      (__attribute__((address_space(3))) void*)l, 16, 0, 0);
}

// ---------------------------------------------------------------------------
// prep: f32 -> bf16 casts (x, W_in, W_out) + q_cls passthrough copy
// ---------------------------------------------------------------------------
__device__ __forceinline__ void cvt4(const float* __restrict__ s, bf16* __restrict__ d) {
  f32x4 v = *(const f32x4*)s;
  bf16x4 o;
  o[0] = (bf16)v[0]; o[1] = (bf16)v[1]; o[2] = (bf16)v[2]; o[3] = (bf16)v[3];
  *(bf16x4*)d = o;
}

__global__ __launch_bounds__(256) void prep_kernel(
    const float* __restrict__ q, const float* __restrict__ win,
    const float* __restrict__ wout, float* __restrict__ out0,
    bf16* __restrict__ xb, bf16* __restrict__ wqb, bf16* __restrict__ wob) {
  long u = (long)blockIdx.x * 256 + threadIdx.x;
  const long NX4 = 1605632, NWQ4 = 196608, NWO4 = 65536, NQC4 = 1024;
  if (u < NX4) { cvt4(q + 4096 + u * 4, xb + u * 4); return; }
  u -= NX4;
  if (u < NWQ4) { cvt4(win + u * 4, wqb + u * 4); return; }
  u -= NWQ4;
  if (u < NWO4) { cvt4(wout + u * 4, wob + u * 4); return; }
  u -= NWO4;
  if (u < NQC4) { *(f32x4*)(out0 + u * 4) = *(const f32x4*)(q + u * 4); }
}

// ---------------------------------------------------------------------------
// GEMM: C[m][n] = sum_k A[m][k] * B[n][k] + bias[n]
// 128x128 tile, BK=32, 4 waves, global_load_lds staging, XCD swizzle.
// ---------------------------------------------------------------------------
template <bool OUTF32>
__global__ __launch_bounds__(256) void gemm_bt(
    const bf16* __restrict__ A, const bf16* __restrict__ Bm,
    const float* __restrict__ bias, bf16* __restrict__ Cb,
    float* __restrict__ Cf, int N, int K, long coff) {
  __shared__ bf16 As[128 * 32];
  __shared__ bf16 Bs[128 * 32];
  const int tid = threadIdx.x;
  const int wid = tid >> 6, lane = tid & 63;
  const int lr = lane & 15, lg = lane >> 4;

  const int nwg = gridDim.x * gridDim.y;        // multiple of 8
  const int orig = blockIdx.y * gridDim.x + blockIdx.x;
  const int cpx = nwg >> 3;
  const int swz = (orig & 7) * cpx + (orig >> 3);
  const int m0 = (swz / gridDim.x) * 128;
  const int n0 = (swz % gridDim.x) * 128;

  const int wr = wid >> 1, wc = wid & 1;
  const int srow = lane >> 2;                   // 0..15
  const int scol = (lane & 3) * 8;              // 0,8,16,24

  f32x4 acc[4][4] = {};

  for (int kt = 0; kt < K; kt += 32) {
    __syncthreads();
#pragma unroll
    for (int j = 0; j < 2; ++j) {
      int r0 = wid * 32 + j * 16;
      gl2lds16(A + (size_t)(m0 + r0 + srow) * K + kt + scol, As + r0 * 32);
      gl2lds16(Bm + (size_t)(n0 + r0 + srow) * K + kt + scol, Bs + r0 * 32);
    }
    __syncthreads();

    bf16x8 af[4], bfr[4];
#pragma unroll
    for (int m = 0; m < 4; ++m)
      af[m] = *(const bf16x8*)(As + (wr * 64 + m * 16 + lr) * 32 + lg * 8);
#pragma unroll
    for (int n = 0; n < 4; ++n)
      bfr[n] = *(const bf16x8*)(Bs + (wc * 64 + n * 16 + lr) * 32 + lg * 8);
#pragma unroll
    for (int m = 0; m < 4; ++m)
#pragma unroll
      for (int n = 0; n < 4; ++n)
        acc[m][n] = MFMA16(af[m], bfr[n], acc[m][n]);
  }

#pragma unroll
  for (int m = 0; m < 4; ++m) {
    int row = m0 + wr * 64 + m * 16 + lg * 4;
#pragma unroll
    for (int n = 0; n < 4; ++n) {
      int col = n0 + wc * 64 + n * 16 + lr;
      float bv = bias[col];
#pragma unroll
      for (int i = 0; i < 4; ++i) {
        float v = acc[m][n][i] + bv;
        if (OUTF32)
          __builtin_nontemporal_store(v, Cf + coff + (size_t)(row + i) * N + col);
        else
          Cb[(size_t)(row + i) * N + col] = (bf16)v;
      }
    }
  }
}

// ---------------------------------------------------------------------------
// Spatial attention, swapped-QK^T + LDS-realigned attn stores.
// r5-r9 analysis: attn rows are 784B, so direct fragment stores form 64B
// transactions at (q*16 mod 64) offsets -> EVERY one straddles two 64B
// sectors -> partial-sector RMW (+48MB fetch, +83MB write). Fix: stage the
// wave's 16x196 f32 tile in LDS in exact global stripe order (16*784 =
// 12544B, 64B-aligned stripes), then stream out with aligned dwordx4.
// Per-wave private tile -> no barriers. LDS total 162,304B -> 1 block/CU.
// ---------------------------------------------------------------------------
__global__ __launch_bounds__(512) void spatial_attn(
    const bf16* __restrict__ qkv, float* __restrict__ attn_out,
    bf16* __restrict__ outs) {
  __shared__ bf16 Kl[224][72];        // [k-row][d]
  __shared__ bf16 Vt[64][232];        // [d][k-row]
  __shared__ float Stg[8 * 3136];     // per-wave 16x196 f32 stripe tile

  const int tid = threadIdx.x;
  const int wid = tid >> 6, lane = tid & 63;
  const int lr = lane & 15, lg = lane >> 4;
  const int batch = blockIdx.x;            // (h*8 + bb)*8 + ti
  const int ti = batch & 7;
  const int bb = (batch >> 3) & 7;
  const int h = batch >> 6;

  // ---- stage K (row-major, b128 writes), zero-pad rows >=196
  {
    const int p = (tid >> 3);                // 0..63
    const int c = (tid & 7) * 8;
    bf16 zz = (bf16)0.f;
    for (int r0 = 0; r0 < 224; r0 += 64) {
      int pp = r0 + p;
      bf16x8 kv = {zz, zz, zz, zz, zz, zz, zz, zz};
      if (pp < 196) {
        size_t ro = ((size_t)(ti * 196 + pp) * 8 + bb) * 1536 + h * 64 + c;
        kv = *(const bf16x8*)(qkv + ro + 512);
      }
      if (pp < 224) *(bf16x8*)&Kl[pp][c] = kv;
    }
  }
  // ---- stage V transposed: wave w owns cols c=w*8..w*8+7, lane = row
  {
    const int c = wid * 8;
    bf16 zz = (bf16)0.f;
    for (int r0 = 0; r0 < 224; r0 += 64) {
      int pp = r0 + lane;
      bf16x8 vv = {zz, zz, zz, zz, zz, zz, zz, zz};
      if (pp < 196) {
        size_t ro = ((size_t)(ti * 196 + pp) * 8 + bb) * 1536 + h * 64 + c;
        vv = *(const bf16x8*)(qkv + ro + 1024);
      }
      if (pp < 224) {
#pragma unroll
        for (int j = 0; j < 8; ++j) Vt[c + j][pp] = vv[j];
      }
    }
  }
  __syncthreads();

  float* const tile = Stg + wid * 3136;    // wave-private 16x196 f32

  // ---- per-wave 16-row Q tiles; 13 tiles cover 196
  for (int qt = wid; qt < 13; qt += 8) {
    const int q = qt * 16 + lr;              // this lane's q-row
    bf16x8 aq[2];
    {
      int row = q > 195 ? 195 : q;           // clamp; discarded on store
      size_t ro = ((size_t)(ti * 196 + row) * 8 + bb) * 1536 + h * 64;
#pragma unroll
      for (int kk = 0; kk < 2; ++kk)
        aq[kk] = *(const bf16x8*)(qkv + ro + kk * 32 + lg * 8);
    }

    // S^T = K Q^T : lane -> q=lr, k = nn*16 + lg*4 + i
    f32x4 s[14] = {};
#pragma unroll
    for (int nn = 0; nn < 14; ++nn) {
      bf16x8 bk0 = *(const bf16x8*)&Kl[nn * 16 + lr][lg * 8];
      bf16x8 bk1 = *(const bf16x8*)&Kl[nn * 16 + lr][32 + lg * 8];
      s[nn] = MFMA16(bk0, aq[0], s[nn]);     // swapped operands
      s[nn] = MFMA16(bk1, aq[1], s[nn]);
    }

    // scale + mask pad cols (vector-uniform: 196 % 4 == 0)
#pragma unroll
    for (int nn = 0; nn < 14; ++nn) {
      bool pad = (nn * 16 + lg * 4 >= 196);
#pragma unroll
      for (int i = 0; i < 4; ++i)
        s[nn][i] = pad ? -1e30f : s[nn][i] * 0.125f;
    }

    // softmax over k: local 56 + 4-lane group reduce (lanes lr,+16,+32,+48)
    float v = -1e30f;
#pragma unroll
    for (int nn = 0; nn < 14; ++nn)
#pragma unroll
      for (int i = 0; i < 4; ++i) v = fmaxf(v, s[nn][i]);
    v = fmaxf(v, __shfl_xor(v, 16));
    v = fmaxf(v, __shfl_xor(v, 32));
    float sum = 0.f;
#pragma unroll
    for (int nn = 0; nn < 14; ++nn)
#pragma unroll
      for (int i = 0; i < 4; ++i) {
        float e = __expf(s[nn][i] - v);
        s[nn][i] = e;
        sum += e;
      }
    sum += __shfl_xor(sum, 16);
    sum += __shfl_xor(sum, 32);
    const float rinv = 1.f / sum;

    // fused: per kb {normalize -> tile write (LDS) -> pack -> shuffle -> PV}
    const int low = lr + 32 * (lg & 1);
    const int high = low + 16;
    const bool hiN = (lg >> 1) != 0;
    f32x4 o[4] = {};
#pragma unroll
    for (int kb = 0; kb < 7; ++kb) {
      uint32_t px[2], py[2];
#pragma unroll
      for (int t = 0; t < 2; ++t) {
        const int nn = 2 * kb + t;
        f32x4 sv;
#pragma unroll
        for (int i = 0; i < 4; ++i) sv[i] = s[nn][i] * rinv;
        int kbase = nn * 16 + lg * 4;
        if (kbase < 196)
          *(f32x4*)(tile + lr * 196 + kbase) = sv;
        union { bf16x4 h; uint2 u; } pk;
        pk.h[0] = (bf16)sv[0]; pk.h[1] = (bf16)sv[1];
        pk.h[2] = (bf16)sv[2]; pk.h[3] = (bf16)sv[3];
        px[t] = pk.u.x; py[t] = pk.u.y;
      }
      uint32_t a0x = __shfl((int)px[0], low);
      uint32_t a0y = __shfl((int)py[0], low);
      uint32_t a1x = __shfl((int)px[1], low);
      uint32_t a1y = __shfl((int)py[1], low);
      uint32_t b0x = __shfl((int)px[0], high);
      uint32_t b0y = __shfl((int)py[0], high);
      uint32_t b1x = __shfl((int)px[1], high);
      uint32_t b1y = __shfl((int)py[1], high);
      union { uint32_t u[4]; bf16x8 h; } pa;
      pa.u[0] = hiN ? a1x : a0x;
      pa.u[1] = hiN ? a1y : a0y;
      pa.u[2] = hiN ? b1x : b0x;
      pa.u[3] = hiN ? b1y : b0y;
#pragma unroll
      for (int nd = 0; nd < 4; ++nd) {
        bf16x8 vb = *(const bf16x8*)&Vt[nd * 16 + lr][kb * 32 + lg * 8];
        o[nd] = MFMA16(pa.h, vb, o[nd]);
      }
    }

    // write out_s in v_t layout [h][bb][p][ti][d]; o: row=q'=lg*4+i, col=d
#pragma unroll
    for (int i = 0; i < 4; ++i) {
      int p = qt * 16 + lg * 4 + i;
      if (p < 196) {
#pragma unroll
        for (int nd = 0; nd < 4; ++nd) {
          int d = nd * 16 + lr;
          outs[(((size_t)((h * 8 + bb) * 196 + p)) * 8 + ti) * 64 + d] =
              (bf16)o[nd][i];
        }
      }
    }

    // stream the wave's aligned 12544B attn stripe: LDS (linear) -> global
    {
      const int vbytes = (qt == 12) ? 3136 : 12544;  // valid rows x 784B
      const char* src = (const char*)tile;
      char* dst = (char*)(attn_out + (size_t)batch * 38416 + qt * 3136);
#pragma unroll
      for (int j = 0; j < 13; ++j) {
        int x = j * 1024 + lane * 16;
        if (x < vbytes)
          *(f32x4*)(dst + x) = *(const f32x4*)(src + x);
      }
    }
  }
}

// ---------------------------------------------------------------------------
// Temporal attention: 1 wave per (h, bb, p) batch; t=8, dh=64.
// ---------------------------------------------------------------------------
__global__ __launch_bounds__(256) void temporal_attn(
    const bf16* __restrict__ qkv, const bf16* __restrict__ outs,
    bf16* __restrict__ outt) {
  __shared__ bf16 Ql[4][8][72];
  __shared__ bf16 Kc[4][8][72];
  __shared__ bf16 Vl[4][8][64];
  __shared__ float Ps[4][8][8];

  const int tid = threadIdx.x, wid = tid >> 6, lane = tid & 63;
  const int batch = blockIdx.x * 4 + wid;  // (h*8+bb)*196 + p
  const int p = batch % 196;
  const int hb = batch / 196;
  const int bb = hb & 7, h = hb >> 3;

  const int ri = lane >> 3;        // t-row 0..7
  const int c8 = lane & 7;         // 8-elem chunk of d
  {
    size_t ro = ((size_t)(ri * 196 + p) * 8 + bb) * 1536 + h * 64 + c8 * 8;
    *(bf16x8*)&Ql[wid][ri][c8 * 8] = *(const bf16x8*)(qkv + ro);
    *(bf16x8*)&Kc[wid][ri][c8 * 8] = *(const bf16x8*)(qkv + ro + 512);
    *(bf16x8*)&Vl[wid][ri][c8 * 8] =
        *(const bf16x8*)(outs + ((size_t)batch * 8 + ri) * 64 + c8 * 8);
  }
  __syncthreads();

  float s = 0.f;
#pragma unroll
  for (int d = 0; d < 64; d += 8) {
    bf16x8 qv = *(const bf16x8*)&Ql[wid][ri][d];
    bf16x8 kv = *(const bf16x8*)&Kc[wid][c8][d];
#pragma unroll
    for (int e = 0; e < 8; ++e) s += (float)qv[e] * (float)kv[e];
  }
  s *= 0.125f;
  float mxv = s;
#pragma unroll
  for (int d2 = 1; d2 < 8; d2 <<= 1) mxv = fmaxf(mxv, __shfl_xor(mxv, d2));
  float e = __expf(s - mxv);
  float sum = e;
#pragma unroll
  for (int d2 = 1; d2 < 8; d2 <<= 1) sum += __shfl_xor(sum, d2);
  Ps[wid][ri][c8] = e / sum;
  __syncthreads();

  const int d = lane;
#pragma unroll
  for (int ii = 0; ii < 8; ++ii) {
    float o = 0.f;
#pragma unroll
    for (int j = 0; j < 8; ++j) o += Ps[wid][ii][j] * (float)Vl[wid][j][d];
    outt[((size_t)(ii * 196 + p) * 8 + bb) * 512 + h * 64 + d] = (bf16)o;
  }
}

// ---------------------------------------------------------------------------
extern "C" void kernel_launch(void* const* d_in, const int* in_sizes, int n_in,
                              void* d_out, int out_size, void* d_ws,
                              size_t ws_size, hipStream_t stream) {
  (void)in_sizes; (void)n_in; (void)out_size; (void)ws_size;
  const float* q    = (const float*)d_in[0];
  const float* win  = (const float*)d_in[3];
  const float* bin  = (const float*)d_in[4];
  const float* wout = (const float*)d_in[5];
  const float* bout = (const float*)d_in[6];
  float* out0 = (float*)d_out;
  float* attn = out0 + 6426624L;   // 1569*8*512

  // ws layout (64,749,568 bytes total):
  bf16* qkv  = (bf16*)d_ws;                 // 12544*1536
  bf16* outs = qkv + 19267584L;             // 8*8*196*8*64
  bf16* outt = outs + 6422528L;             // 12544*512
  bf16* wob  = outt + 6422528L;             // 512*512

  // gemm1-only scratch inside attn region of d_out (rewritten by spatial):
  bf16* xb  = (bf16*)attn;                  // 12544*512
  bf16* wqb = xb + 6422528L;                // 1536*512

  prep_kernel<<<7300, 256, 0, stream>>>(q, win, wout, out0, xb, wqb, wob);
  gemm_bt<false><<<dim3(12, 98), 256, 0, stream>>>(xb, wqb, bin, qkv, nullptr,
                                                   1536, 512, 0);
  spatial_attn<<<512, 512, 0, stream>>>(qkv, attn, outs);
  temporal_attn<<<3136, 256, 0, stream>>>(qkv, outs, outt);
  gemm_bt<true><<<dim3(4, 98), 256, 0, stream>>>(outt, wob, bout, nullptr,
                                                 out0, 512, 512, 4096);
}

// Round 11
// 102.869 us; speedup vs baseline: 1.5020x; 1.2611x over previous
//
#include <hip/hip_runtime.h>
#include <cstdint>
#include <cstddef>

typedef __bf16 bf16;
typedef __bf16 bf16x8 __attribute__((ext_vector_type(8)));
typedef __bf16 bf16x4 __attribute__((ext_vector_type(4)));
typedef float  f32x4  __attribute__((ext_vector_type(4)));

#define MFMA16(a, b, c) __builtin_amdgcn_mfma_f32_16x16x32_bf16(a, b, c, 0, 0, 0)

// async global->LDS, 16B per lane, dest = wave-uniform base + lane*16
__device__ __forceinline__ void gl2lds16(const bf16* g, bf16* l) {
  __builtin_amdgcn_global_load_lds(
      (const __attribute__((address_space(1))) void*)g,
      (__attribute__((address_space(3))) void*)l, 16, 0, 0);
}

// ---------------------------------------------------------------------------
// prep: f32 -> bf16 casts (x, W_in, W_out) + q_cls passthrough copy
// ---------------------------------------------------------------------------
__device__ __forceinline__ void cvt4(const float* __restrict__ s, bf16* __restrict__ d) {
  f32x4 v = *(const f32x4*)s;
  bf16x4 o;
  o[0] = (bf16)v[0]; o[1] = (bf16)v[1]; o[2] = (bf16)v[2]; o[3] = (bf16)v[3];
  *(bf16x4*)d = o;
}

__global__ __launch_bounds__(256) void prep_kernel(
    const float* __restrict__ q, const float* __restrict__ win,
    const float* __restrict__ wout, float* __restrict__ out0,
    bf16* __restrict__ xb, bf16* __restrict__ wqb, bf16* __restrict__ wob) {
  long u = (long)blockIdx.x * 256 + threadIdx.x;
  const long NX4 = 1605632, NWQ4 = 196608, NWO4 = 65536, NQC4 = 1024;
  if (u < NX4) { cvt4(q + 4096 + u * 4, xb + u * 4); return; }
  u -= NX4;
  if (u < NWQ4) { cvt4(win + u * 4, wqb + u * 4); return; }
  u -= NWQ4;
  if (u < NWO4) { cvt4(wout + u * 4, wob + u * 4); return; }
  u -= NWO4;
  if (u < NQC4) { *(f32x4*)(out0 + u * 4) = *(const f32x4*)(q + u * 4); }
}

// ---------------------------------------------------------------------------
// GEMM: C[m][n] = sum_k A[m][k] * B[n][k] + bias[n]
// 128x128 tile, BK=32, 4 waves, global_load_lds staging, XCD swizzle.
// ---------------------------------------------------------------------------
template <bool OUTF32>
__global__ __launch_bounds__(256) void gemm_bt(
    const bf16* __restrict__ A, const bf16* __restrict__ Bm,
    const float* __restrict__ bias, bf16* __restrict__ Cb,
    float* __restrict__ Cf, int N, int K, long coff) {
  __shared__ bf16 As[128 * 32];
  __shared__ bf16 Bs[128 * 32];
  const int tid = threadIdx.x;
  const int wid = tid >> 6, lane = tid & 63;
  const int lr = lane & 15, lg = lane >> 4;

  const int nwg = gridDim.x * gridDim.y;        // multiple of 8
  const int orig = blockIdx.y * gridDim.x + blockIdx.x;
  const int cpx = nwg >> 3;
  const int swz = (orig & 7) * cpx + (orig >> 3);
  const int m0 = (swz / gridDim.x) * 128;
  const int n0 = (swz % gridDim.x) * 128;

  const int wr = wid >> 1, wc = wid & 1;
  const int srow = lane >> 2;                   // 0..15
  const int scol = (lane & 3) * 8;              // 0,8,16,24

  f32x4 acc[4][4] = {};

  for (int kt = 0; kt < K; kt += 32) {
    __syncthreads();
#pragma unroll
    for (int j = 0; j < 2; ++j) {
      int r0 = wid * 32 + j * 16;
      gl2lds16(A + (size_t)(m0 + r0 + srow) * K + kt + scol, As + r0 * 32);
      gl2lds16(Bm + (size_t)(n0 + r0 + srow) * K + kt + scol, Bs + r0 * 32);
    }
    __syncthreads();

    bf16x8 af[4], bfr[4];
#pragma unroll
    for (int m = 0; m < 4; ++m)
      af[m] = *(const bf16x8*)(As + (wr * 64 + m * 16 + lr) * 32 + lg * 8);
#pragma unroll
    for (int n = 0; n < 4; ++n)
      bfr[n] = *(const bf16x8*)(Bs + (wc * 64 + n * 16 + lr) * 32 + lg * 8);
#pragma unroll
    for (int m = 0; m < 4; ++m)
#pragma unroll
      for (int n = 0; n < 4; ++n)
        acc[m][n] = MFMA16(af[m], bfr[n], acc[m][n]);
  }

#pragma unroll
  for (int m = 0; m < 4; ++m) {
    int row = m0 + wr * 64 + m * 16 + lg * 4;
#pragma unroll
    for (int n = 0; n < 4; ++n) {
      int col = n0 + wc * 64 + n * 16 + lr;
      float bv = bias[col];
#pragma unroll
      for (int i = 0; i < 4; ++i) {
        float v = acc[m][n][i] + bv;
        if (OUTF32)
          __builtin_nontemporal_store(v, Cf + coff + (size_t)(row + i) * N + col);
        else
          Cb[(size_t)(row + i) * N + col] = (bf16)v;
      }
    }
  }
}

// ---------------------------------------------------------------------------
// Spatial attention, swapped-QK^T, 1024 threads (16 waves = 4 waves/SIMD).
// r10 showed 2 waves/SIMD -> 3.7 TB/s; this doubles MLP for latency hiding
// and halves the compute span (one q-tile per wave, 13 active waves).
// attn staged in LDS as bf16 (13 x 16x196 x 2B = 81.5KB; total 143.5KB),
// expanded to f32 on the aligned copy-out (bf16->f32 exact bit-shift;
// adds <=0.002 abs error on output 1, threshold 0.0756).
// ---------------------------------------------------------------------------
__global__ __launch_bounds__(1024) void spatial_attn(
    const bf16* __restrict__ qkv, float* __restrict__ attn_out,
    bf16* __restrict__ outs) {
  __shared__ bf16 Kl[224][72];        // [k-row][d]
  __shared__ bf16 Vt[64][232];        // [d][k-row]
  __shared__ bf16 StgB[13 * 3136];    // per-tile 16x196 bf16 stripe

  const int tid = threadIdx.x;
  const int wid = tid >> 6, lane = tid & 63;
  const int lr = lane & 15, lg = lane >> 4;
  const int batch = blockIdx.x;            // (h*8 + bb)*8 + ti
  const int ti = batch & 7;
  const int bb = (batch >> 3) & 7;
  const int h = batch >> 6;

  // ---- stage K (row-major, b128 writes), zero-pad rows >=196; 128 rows/iter
  {
    const int p = (tid >> 3);                // 0..127
    const int c = (tid & 7) * 8;
    bf16 zz = (bf16)0.f;
#pragma unroll
    for (int r0 = 0; r0 < 256; r0 += 128) {
      int pp = r0 + p;
      bf16x8 kv = {zz, zz, zz, zz, zz, zz, zz, zz};
      if (pp < 196) {
        size_t ro = ((size_t)(ti * 196 + pp) * 8 + bb) * 1536 + h * 64 + c;
        kv = *(const bf16x8*)(qkv + ro + 512);
      }
      if (pp < 224) *(bf16x8*)&Kl[pp][c] = kv;
    }
  }
  // ---- stage V transposed: wave w: cols (w&7)*8..+7, rows (w>>3)*64+lane
  {
    const int c = (wid & 7) * 8;
    const int rbase = (wid >> 3) * 64 + lane;
    bf16 zz = (bf16)0.f;
#pragma unroll
    for (int r0 = 0; r0 < 256; r0 += 128) {
      int pp = r0 + rbase;
      bf16x8 vv = {zz, zz, zz, zz, zz, zz, zz, zz};
      if (pp < 196) {
        size_t ro = ((size_t)(ti * 196 + pp) * 8 + bb) * 1536 + h * 64 + c;
        vv = *(const bf16x8*)(qkv + ro + 1024);
      }
      if (pp < 224) {
#pragma unroll
        for (int j = 0; j < 8; ++j) Vt[c + j][pp] = vv[j];
      }
    }
  }
  __syncthreads();

  // ---- one 16-row q-tile per wave; waves 13..15 idle (no barrier below)
  const int qt = wid;
  if (qt < 13) {
    const int q = qt * 16 + lr;              // this lane's q-row
    bf16x8 aq[2];
    {
      int row = q > 195 ? 195 : q;           // clamp; discarded on store
      size_t ro = ((size_t)(ti * 196 + row) * 8 + bb) * 1536 + h * 64;
#pragma unroll
      for (int kk = 0; kk < 2; ++kk)
        aq[kk] = *(const bf16x8*)(qkv + ro + kk * 32 + lg * 8);
    }

    // S^T = K Q^T : lane -> q=lr, k = nn*16 + lg*4 + i
    f32x4 s[14] = {};
#pragma unroll
    for (int nn = 0; nn < 14; ++nn) {
      bf16x8 bk0 = *(const bf16x8*)&Kl[nn * 16 + lr][lg * 8];
      bf16x8 bk1 = *(const bf16x8*)&Kl[nn * 16 + lr][32 + lg * 8];
      s[nn] = MFMA16(bk0, aq[0], s[nn]);     // swapped operands
      s[nn] = MFMA16(bk1, aq[1], s[nn]);
    }

    // scale + mask pad cols (vector-uniform: 196 % 4 == 0)
#pragma unroll
    for (int nn = 0; nn < 14; ++nn) {
      bool pad = (nn * 16 + lg * 4 >= 196);
#pragma unroll
      for (int i = 0; i < 4; ++i)
        s[nn][i] = pad ? -1e30f : s[nn][i] * 0.125f;
    }

    // softmax over k: local 56 + 4-lane group reduce (lanes lr,+16,+32,+48)
    float v = -1e30f;
#pragma unroll
    for (int nn = 0; nn < 14; ++nn)
#pragma unroll
      for (int i = 0; i < 4; ++i) v = fmaxf(v, s[nn][i]);
    v = fmaxf(v, __shfl_xor(v, 16));
    v = fmaxf(v, __shfl_xor(v, 32));
    float sum = 0.f;
#pragma unroll
    for (int nn = 0; nn < 14; ++nn)
#pragma unroll
      for (int i = 0; i < 4; ++i) {
        float e = __expf(s[nn][i] - v);
        s[nn][i] = e;
        sum += e;
      }
    sum += __shfl_xor(sum, 16);
    sum += __shfl_xor(sum, 32);
    const float rinv = 1.f / sum;

    // fused: per kb {normalize -> bf16 pack -> Stg write -> shuffle -> PV}
    bf16* const tile = StgB + qt * 3136;     // this tile's 16x196 bf16
    const int low = lr + 32 * (lg & 1);
    const int high = low + 16;
    const bool hiN = (lg >> 1) != 0;
    f32x4 o[4] = {};
#pragma unroll
    for (int kb = 0; kb < 7; ++kb) {
      uint32_t px[2], py[2];
#pragma unroll
      for (int t = 0; t < 2; ++t) {
        const int nn = 2 * kb + t;
        f32x4 sv;
#pragma unroll
        for (int i = 0; i < 4; ++i) sv[i] = s[nn][i] * rinv;
        union { bf16x4 h; uint2 u; } pk;
        pk.h[0] = (bf16)sv[0]; pk.h[1] = (bf16)sv[1];
        pk.h[2] = (bf16)sv[2]; pk.h[3] = (bf16)sv[3];
        int kbase = nn * 16 + lg * 4;
        if (kbase < 196)
          *(uint2*)((char*)tile + lr * 392 + kbase * 2) = pk.u;
        px[t] = pk.u.x; py[t] = pk.u.y;
      }
      uint32_t a0x = __shfl((int)px[0], low);
      uint32_t a0y = __shfl((int)py[0], low);
      uint32_t a1x = __shfl((int)px[1], low);
      uint32_t a1y = __shfl((int)py[1], low);
      uint32_t b0x = __shfl((int)px[0], high);
      uint32_t b0y = __shfl((int)py[0], high);
      uint32_t b1x = __shfl((int)px[1], high);
      uint32_t b1y = __shfl((int)py[1], high);
      union { uint32_t u[4]; bf16x8 h; } pa;
      pa.u[0] = hiN ? a1x : a0x;
      pa.u[1] = hiN ? a1y : a0y;
      pa.u[2] = hiN ? b1x : b0x;
      pa.u[3] = hiN ? b1y : b0y;
#pragma unroll
      for (int nd = 0; nd < 4; ++nd) {
        bf16x8 vb = *(const bf16x8*)&Vt[nd * 16 + lr][kb * 32 + lg * 8];
        o[nd] = MFMA16(pa.h, vb, o[nd]);
      }
    }

    // write out_s in v_t layout [h][bb][p][ti][d]; o: row=q'=lg*4+i, col=d
#pragma unroll
    for (int i = 0; i < 4; ++i) {
      int p = qt * 16 + lg * 4 + i;
      if (p < 196) {
#pragma unroll
        for (int nd = 0; nd < 4; ++nd) {
          int d = nd * 16 + lr;
          outs[(((size_t)((h * 8 + bb) * 196 + p)) * 8 + ti) * 64 + d] =
              (bf16)o[nd][i];
        }
      }
    }

    // aligned copy-out: LDS bf16 stripe -> global f32 (exact bit expand)
    {
      const int vbytes = (qt == 12) ? 3136 : 12544;  // f32 bytes (4|16 rows)
      char* dst = (char*)(attn_out + (size_t)batch * 38416 + qt * 3136);
      const char* src = (const char*)tile;
#pragma unroll
      for (int j = 0; j < 13; ++j) {
        int x = j * 1024 + lane * 16;
        if (x < vbytes) {
          uint2 u = *(const uint2*)(src + (x >> 1));
          union { uint32_t b; float f; } c0, c1, c2, c3;
          c0.b = (u.x & 0xffffu) << 16; c1.b = u.x & 0xffff0000u;
          c2.b = (u.y & 0xffffu) << 16; c3.b = u.y & 0xffff0000u;
          f32x4 ov; ov[0] = c0.f; ov[1] = c1.f; ov[2] = c2.f; ov[3] = c3.f;
          *(f32x4*)(dst + x) = ov;
        }
      }
    }
  }
}

// ---------------------------------------------------------------------------
// Temporal attention: 1 wave per (h, bb, p) batch; t=8, dh=64.
// ---------------------------------------------------------------------------
__global__ __launch_bounds__(256) void temporal_attn(
    const bf16* __restrict__ qkv, const bf16* __restrict__ outs,
    bf16* __restrict__ outt) {
  __shared__ bf16 Ql[4][8][72];
  __shared__ bf16 Kc[4][8][72];
  __shared__ bf16 Vl[4][8][64];
  __shared__ float Ps[4][8][8];

  const int tid = threadIdx.x, wid = tid >> 6, lane = tid & 63;
  const int batch = blockIdx.x * 4 + wid;  // (h*8+bb)*196 + p
  const int p = batch % 196;
  const int hb = batch / 196;
  const int bb = hb & 7, h = hb >> 3;

  const int ri = lane >> 3;        // t-row 0..7
  const int c8 = lane & 7;         // 8-elem chunk of d
  {
    size_t ro = ((size_t)(ri * 196 + p) * 8 + bb) * 1536 + h * 64 + c8 * 8;
    *(bf16x8*)&Ql[wid][ri][c8 * 8] = *(const bf16x8*)(qkv + ro);
    *(bf16x8*)&Kc[wid][ri][c8 * 8] = *(const bf16x8*)(qkv + ro + 512);
    *(bf16x8*)&Vl[wid][ri][c8 * 8] =
        *(const bf16x8*)(outs + ((size_t)batch * 8 + ri) * 64 + c8 * 8);
  }
  __syncthreads();

  float s = 0.f;
#pragma unroll
  for (int d = 0; d < 64; d += 8) {
    bf16x8 qv = *(const bf16x8*)&Ql[wid][ri][d];
    bf16x8 kv = *(const bf16x8*)&Kc[wid][c8][d];
#pragma unroll
    for (int e = 0; e < 8; ++e) s += (float)qv[e] * (float)kv[e];
  }
  s *= 0.125f;
  float mxv = s;
#pragma unroll
  for (int d2 = 1; d2 < 8; d2 <<= 1) mxv = fmaxf(mxv, __shfl_xor(mxv, d2));
  float e = __expf(s - mxv);
  float sum = e;
#pragma unroll
  for (int d2 = 1; d2 < 8; d2 <<= 1) sum += __shfl_xor(sum, d2);
  Ps[wid][ri][c8] = e / sum;
  __syncthreads();

  const int d = lane;
#pragma unroll
  for (int ii = 0; ii < 8; ++ii) {
    float o = 0.f;
#pragma unroll
    for (int j = 0; j < 8; ++j) o += Ps[wid][ii][j] * (float)Vl[wid][j][d];
    outt[((size_t)(ii * 196 + p) * 8 + bb) * 512 + h * 64 + d] = (bf16)o;
  }
}

// ---------------------------------------------------------------------------
extern "C" void kernel_launch(void* const* d_in, const int* in_sizes, int n_in,
                              void* d_out, int out_size, void* d_ws,
                              size_t ws_size, hipStream_t stream) {
  (void)in_sizes; (void)n_in; (void)out_size; (void)ws_size;
  const float* q    = (const float*)d_in[0];
  const float* win  = (const float*)d_in[3];
  const float* bin  = (const float*)d_in[4];
  const float* wout = (const float*)d_in[5];
  const float* bout = (const float*)d_in[6];
  float* out0 = (float*)d_out;
  float* attn = out0 + 6426624L;   // 1569*8*512

  // ws layout (64,749,568 bytes total):
  bf16* qkv  = (bf16*)d_ws;                 // 12544*1536
  bf16* outs = qkv + 19267584L;             // 8*8*196*8*64
  bf16* outt = outs + 6422528L;             // 12544*512
  bf16* wob  = outt + 6422528L;             // 512*512

  // gemm1-only scratch inside attn region of d_out (rewritten by spatial):
  bf16* xb  = (bf16*)attn;                  // 12544*512
  bf16* wqb = xb + 6422528L;                // 1536*512

  prep_kernel<<<7300, 256, 0, stream>>>(q, win, wout, out0, xb, wqb, wob);
  gemm_bt<false><<<dim3(12, 98), 256, 0, stream>>>(xb, wqb, bin, qkv, nullptr,
                                                   1536, 512, 0);
  spatial_attn<<<512, 1024, 0, stream>>>(qkv, attn, outs);
  temporal_attn<<<3136, 256, 0, stream>>>(qkv, outs, outt);
  gemm_bt<true><<<dim3(4, 98), 256, 0, stream>>>(outt, wob, bout, nullptr,
                                                 out0, 512, 512, 4096);
}

// Round 12
// 102.442 us; speedup vs baseline: 1.5082x; 1.0042x over previous
//
#include <hip/hip_runtime.h>
#include <cstdint>
#include <cstddef>

typedef __bf16 bf16;
typedef __bf16 bf16x8 __attribute__((ext_vector_type(8)));
typedef __bf16 bf16x4 __attribute__((ext_vector_type(4)));
typedef float  f32x4  __attribute__((ext_vector_type(4)));

#define MFMA16(a, b, c) __builtin_amdgcn_mfma_f32_16x16x32_bf16(a, b, c, 0, 0, 0)

// async global->LDS, 16B per lane, dest = wave-uniform base + lane*16
__device__ __forceinline__ void gl2lds16(const bf16* g, bf16* l) {
  __builtin_amdgcn_global_load_lds(
      (const __attribute__((address_space(1))) void*)g,
      (__attribute__((address_space(3))) void*)l, 16, 0, 0);
}

// ---------------------------------------------------------------------------
// prep: f32 -> bf16 casts (x, W_in, W_out) + q_cls passthrough copy
// ---------------------------------------------------------------------------
__device__ __forceinline__ void cvt4(const float* __restrict__ s, bf16* __restrict__ d) {
  f32x4 v = *(const f32x4*)s;
  bf16x4 o;
  o[0] = (bf16)v[0]; o[1] = (bf16)v[1]; o[2] = (bf16)v[2]; o[3] = (bf16)v[3];
  *(bf16x4*)d = o;
}

__global__ __launch_bounds__(256) void prep_kernel(
    const float* __restrict__ q, const float* __restrict__ win,
    const float* __restrict__ wout, float* __restrict__ out0,
    bf16* __restrict__ xb, bf16* __restrict__ wqb, bf16* __restrict__ wob) {
  long u = (long)blockIdx.x * 256 + threadIdx.x;
  const long NX4 = 1605632, NWQ4 = 196608, NWO4 = 65536, NQC4 = 1024;
  if (u < NX4) { cvt4(q + 4096 + u * 4, xb + u * 4); return; }
  u -= NX4;
  if (u < NWQ4) { cvt4(win + u * 4, wqb + u * 4); return; }
  u -= NWQ4;
  if (u < NWO4) { cvt4(wout + u * 4, wob + u * 4); return; }
  u -= NWO4;
  if (u < NQC4) { *(f32x4*)(out0 + u * 4) = *(const f32x4*)(q + u * 4); }
}

// ---------------------------------------------------------------------------
// GEMM: C[m][n] = sum_k A[m][k] * B[n][k] + bias[n]
// 128x128 tile, BK=32, 4 waves, global_load_lds staging, XCD swizzle.
// ---------------------------------------------------------------------------
template <bool OUTF32>
__global__ __launch_bounds__(256) void gemm_bt(
    const bf16* __restrict__ A, const bf16* __restrict__ Bm,
    const float* __restrict__ bias, bf16* __restrict__ Cb,
    float* __restrict__ Cf, int N, int K, long coff) {
  __shared__ bf16 As[128 * 32];
  __shared__ bf16 Bs[128 * 32];
  const int tid = threadIdx.x;
  const int wid = tid >> 6, lane = tid & 63;
  const int lr = lane & 15, lg = lane >> 4;

  const int nwg = gridDim.x * gridDim.y;        // multiple of 8
  const int orig = blockIdx.y * gridDim.x + blockIdx.x;
  const int cpx = nwg >> 3;
  const int swz = (orig & 7) * cpx + (orig >> 3);
  const int m0 = (swz / gridDim.x) * 128;
  const int n0 = (swz % gridDim.x) * 128;

  const int wr = wid >> 1, wc = wid & 1;
  const int srow = lane >> 2;                   // 0..15
  const int scol = (lane & 3) * 8;              // 0,8,16,24

  f32x4 acc[4][4] = {};

  for (int kt = 0; kt < K; kt += 32) {
    __syncthreads();
#pragma unroll
    for (int j = 0; j < 2; ++j) {
      int r0 = wid * 32 + j * 16;
      gl2lds16(A + (size_t)(m0 + r0 + srow) * K + kt + scol, As + r0 * 32);
      gl2lds16(Bm + (size_t)(n0 + r0 + srow) * K + kt + scol, Bs + r0 * 32);
    }
    __syncthreads();

    bf16x8 af[4], bfr[4];
#pragma unroll
    for (int m = 0; m < 4; ++m)
      af[m] = *(const bf16x8*)(As + (wr * 64 + m * 16 + lr) * 32 + lg * 8);
#pragma unroll
    for (int n = 0; n < 4; ++n)
      bfr[n] = *(const bf16x8*)(Bs + (wc * 64 + n * 16 + lr) * 32 + lg * 8);
#pragma unroll
    for (int m = 0; m < 4; ++m)
#pragma unroll
      for (int n = 0; n < 4; ++n)
        acc[m][n] = MFMA16(af[m], bfr[n], acc[m][n]);
  }

#pragma unroll
  for (int m = 0; m < 4; ++m) {
    int row = m0 + wr * 64 + m * 16 + lg * 4;
#pragma unroll
    for (int n = 0; n < 4; ++n) {
      int col = n0 + wc * 64 + n * 16 + lr;
      float bv = bias[col];
#pragma unroll
      for (int i = 0; i < 4; ++i) {
        float v = acc[m][n][i] + bv;
        if (OUTF32)
          __builtin_nontemporal_store(v, Cf + coff + (size_t)(row + i) * N + col);
        else
          Cb[(size_t)(row + i) * N + col] = (bf16)v;
      }
    }
  }
}

// ---------------------------------------------------------------------------
// Spatial attention, swapped-QK^T, 1024 threads (16 waves), 1 block/CU.
// This round: K staged via global_load_lds with pre-swizzled source (linear
// Kl[224][64], read-XOR (kk*4+lg)^(lr&7) involution -> 2-way banks); pad
// rows via source clamp (S pad-cols masked pre-softmax and P[pad]=0, so
// pad-row CONTENT is irrelevant); Q loads hoisted above the barrier;
// s_setprio(1) around both MFMA clusters (T5, attn-proven).
// ---------------------------------------------------------------------------
__global__ __launch_bounds__(1024) void spatial_attn(
    const bf16* __restrict__ qkv, float* __restrict__ attn_out,
    bf16* __restrict__ outs) {
  __shared__ bf16 Kl[224 * 64];       // linear rows of 128B, swizzled chunks
  __shared__ bf16 Vt[64][232];        // [d][k-row]
  __shared__ bf16 StgB[13 * 3136];    // per-tile 16x196 bf16 stripe

  const int tid = threadIdx.x;
  const int wid = tid >> 6, lane = tid & 63;
  const int lr = lane & 15, lg = lane >> 4;
  const int batch = blockIdx.x;            // (h*8 + bb)*8 + ti
  const int ti = batch & 7;
  const int bb = (batch >> 3) & 7;
  const int h = batch >> 6;

  // ---- stage K via gl2lds: instr j covers rows j*8..j*8+7 (28 instrs).
  // LDS slot (row, s) holds K chunk s ^ (row&7); row&7 == lane>>3 here.
  {
    const int slot = lane & 7, r8 = lane >> 3;
    const int chunk = slot ^ r8;
#pragma unroll
    for (int t = 0; t < 2; ++t) {
      int j = wid + t * 16;
      if (j < 28) {
        int row = j * 8 + r8;
        int grow = row > 195 ? 195 : row;       // pad rows: content unused
        const bf16* src = qkv +
            ((size_t)(ti * 196 + grow) * 8 + bb) * 1536 + h * 64 + 512 +
            chunk * 8;
        gl2lds16(src, Kl + j * 512);
      }
    }
  }
  // ---- stage V transposed: wave w: cols (w&7)*8..+7, rows (w>>3)*64+lane
  {
    const int c = (wid & 7) * 8;
    const int rbase = (wid >> 3) * 64 + lane;
#pragma unroll
    for (int r0 = 0; r0 < 256; r0 += 128) {
      int pp = r0 + rbase;
      if (pp < 224) {
        int gp = pp > 195 ? 195 : pp;           // pad rows: P=0 covers
        bf16x8 vv = *(const bf16x8*)(
            qkv + ((size_t)(ti * 196 + gp) * 8 + bb) * 1536 + h * 64 + 1024 + c);
#pragma unroll
        for (int j = 0; j < 8; ++j) Vt[c + j][pp] = vv[j];
      }
    }
  }

  // ---- hoisted Q load (independent of LDS; hides under staging+barrier)
  const int qt = wid;
  bf16x8 aq[2];
  if (qt < 13) {
    int row = qt * 16 + lr;
    if (row > 195) row = 195;                   // clamp; discarded on store
    size_t ro = ((size_t)(ti * 196 + row) * 8 + bb) * 1536 + h * 64;
#pragma unroll
    for (int kk = 0; kk < 2; ++kk)
      aq[kk] = *(const bf16x8*)(qkv + ro + kk * 32 + lg * 8);
  }
  __syncthreads();

  // ---- one 16-row q-tile per wave; waves 13..15 idle (no barrier below)
  if (qt < 13) {
    const int q = qt * 16 + lr;              // this lane's q-row
    const int x7 = lr & 7;                   // row&7 for swizzled K reads

    // S^T = K Q^T : lane -> q=lr, k = nn*16 + lg*4 + i
    f32x4 s[14] = {};
    __builtin_amdgcn_s_setprio(1);
#pragma unroll
    for (int nn = 0; nn < 14; ++nn) {
      const int krow = nn * 16 + lr;
      bf16x8 bk0 = *(const bf16x8*)&Kl[krow * 64 + ((lg ^ x7) * 8)];
      bf16x8 bk1 = *(const bf16x8*)&Kl[krow * 64 + (((4 + lg) ^ x7) * 8)];
      s[nn] = MFMA16(bk0, aq[0], s[nn]);     // swapped operands
      s[nn] = MFMA16(bk1, aq[1], s[nn]);
    }
    __builtin_amdgcn_s_setprio(0);

    // scale + mask pad cols (vector-uniform: 196 % 4 == 0)
#pragma unroll
    for (int nn = 0; nn < 14; ++nn) {
      bool pad = (nn * 16 + lg * 4 >= 196);
#pragma unroll
      for (int i = 0; i < 4; ++i)
        s[nn][i] = pad ? -1e30f : s[nn][i] * 0.125f;
    }

    // softmax over k: local 56 + 4-lane group reduce (lanes lr,+16,+32,+48)
    float v = -1e30f;
#pragma unroll
    for (int nn = 0; nn < 14; ++nn)
#pragma unroll
      for (int i = 0; i < 4; ++i) v = fmaxf(v, s[nn][i]);
    v = fmaxf(v, __shfl_xor(v, 16));
    v = fmaxf(v, __shfl_xor(v, 32));
    float sum = 0.f;
#pragma unroll
    for (int nn = 0; nn < 14; ++nn)
#pragma unroll
      for (int i = 0; i < 4; ++i) {
        float e = __expf(s[nn][i] - v);
        s[nn][i] = e;
        sum += e;
      }
    sum += __shfl_xor(sum, 16);
    sum += __shfl_xor(sum, 32);
    const float rinv = 1.f / sum;

    // fused: per kb {normalize -> bf16 pack -> Stg write -> shuffle -> PV}
    bf16* const tile = StgB + qt * 3136;     // this tile's 16x196 bf16
    const int low = lr + 32 * (lg & 1);
    const int high = low + 16;
    const bool hiN = (lg >> 1) != 0;
    f32x4 o[4] = {};
#pragma unroll
    for (int kb = 0; kb < 7; ++kb) {
      uint32_t px[2], py[2];
#pragma unroll
      for (int t = 0; t < 2; ++t) {
        const int nn = 2 * kb + t;
        f32x4 sv;
#pragma unroll
        for (int i = 0; i < 4; ++i) sv[i] = s[nn][i] * rinv;
        union { bf16x4 h; uint2 u; } pk;
        pk.h[0] = (bf16)sv[0]; pk.h[1] = (bf16)sv[1];
        pk.h[2] = (bf16)sv[2]; pk.h[3] = (bf16)sv[3];
        int kbase = nn * 16 + lg * 4;
        if (kbase < 196)
          *(uint2*)((char*)tile + lr * 392 + kbase * 2) = pk.u;
        px[t] = pk.u.x; py[t] = pk.u.y;
      }
      uint32_t a0x = __shfl((int)px[0], low);
      uint32_t a0y = __shfl((int)py[0], low);
      uint32_t a1x = __shfl((int)px[1], low);
      uint32_t a1y = __shfl((int)py[1], low);
      uint32_t b0x = __shfl((int)px[0], high);
      uint32_t b0y = __shfl((int)py[0], high);
      uint32_t b1x = __shfl((int)px[1], high);
      uint32_t b1y = __shfl((int)py[1], high);
      union { uint32_t u[4]; bf16x8 h; } pa;
      pa.u[0] = hiN ? a1x : a0x;
      pa.u[1] = hiN ? a1y : a0y;
      pa.u[2] = hiN ? b1x : b0x;
      pa.u[3] = hiN ? b1y : b0y;
      __builtin_amdgcn_s_setprio(1);
#pragma unroll
      for (int nd = 0; nd < 4; ++nd) {
        bf16x8 vb = *(const bf16x8*)&Vt[nd * 16 + lr][kb * 32 + lg * 8];
        o[nd] = MFMA16(pa.h, vb, o[nd]);
      }
      __builtin_amdgcn_s_setprio(0);
    }

    // write out_s in v_t layout [h][bb][p][ti][d]; o: row=q'=lg*4+i, col=d
#pragma unroll
    for (int i = 0; i < 4; ++i) {
      int p = qt * 16 + lg * 4 + i;
      if (p < 196) {
#pragma unroll
        for (int nd = 0; nd < 4; ++nd) {
          int d = nd * 16 + lr;
          outs[(((size_t)((h * 8 + bb) * 196 + p)) * 8 + ti) * 64 + d] =
              (bf16)o[nd][i];
        }
      }
    }

    // aligned copy-out: LDS bf16 stripe -> global f32 (exact bit expand)
    {
      const int vbytes = (qt == 12) ? 3136 : 12544;  // f32 bytes (4|16 rows)
      char* dst = (char*)(attn_out + (size_t)batch * 38416 + qt * 3136);
      const char* src = (const char*)tile;
#pragma unroll
      for (int j = 0; j < 13; ++j) {
        int x = j * 1024 + lane * 16;
        if (x < vbytes) {
          uint2 u = *(const uint2*)(src + (x >> 1));
          union { uint32_t b; float f; } c0, c1, c2, c3;
          c0.b = (u.x & 0xffffu) << 16; c1.b = u.x & 0xffff0000u;
          c2.b = (u.y & 0xffffu) << 16; c3.b = u.y & 0xffff0000u;
          f32x4 ov; ov[0] = c0.f; ov[1] = c1.f; ov[2] = c2.f; ov[3] = c3.f;
          *(f32x4*)(dst + x) = ov;
        }
      }
    }
  }
}

// ---------------------------------------------------------------------------
// Temporal attention: 1 wave per (h, bb, p) batch; t=8, dh=64.
// ---------------------------------------------------------------------------
__global__ __launch_bounds__(256) void temporal_attn(
    const bf16* __restrict__ qkv, const bf16* __restrict__ outs,
    bf16* __restrict__ outt) {
  __shared__ bf16 Ql[4][8][72];
  __shared__ bf16 Kc[4][8][72];
  __shared__ bf16 Vl[4][8][64];
  __shared__ float Ps[4][8][8];

  const int tid = threadIdx.x, wid = tid >> 6, lane = tid & 63;
  const int batch = blockIdx.x * 4 + wid;  // (h*8+bb)*196 + p
  const int p = batch % 196;
  const int hb = batch / 196;
  const int bb = hb & 7, h = hb >> 3;

  const int ri = lane >> 3;        // t-row 0..7
  const int c8 = lane & 7;         // 8-elem chunk of d
  {
    size_t ro = ((size_t)(ri * 196 + p) * 8 + bb) * 1536 + h * 64 + c8 * 8;
    *(bf16x8*)&Ql[wid][ri][c8 * 8] = *(const bf16x8*)(qkv + ro);
    *(bf16x8*)&Kc[wid][ri][c8 * 8] = *(const bf16x8*)(qkv + ro + 512);
    *(bf16x8*)&Vl[wid][ri][c8 * 8] =
        *(const bf16x8*)(outs + ((size_t)batch * 8 + ri) * 64 + c8 * 8);
  }
  __syncthreads();

  float s = 0.f;
#pragma unroll
  for (int d = 0; d < 64; d += 8) {
    bf16x8 qv = *(const bf16x8*)&Ql[wid][ri][d];
    bf16x8 kv = *(const bf16x8*)&Kc[wid][c8][d];
#pragma unroll
    for (int e = 0; e < 8; ++e) s += (float)qv[e] * (float)kv[e];
  }
  s *= 0.125f;
  float mxv = s;
#pragma unroll
  for (int d2 = 1; d2 < 8; d2 <<= 1) mxv = fmaxf(mxv, __shfl_xor(mxv, d2));
  float e = __expf(s - mxv);
  float sum = e;
#pragma unroll
  for (int d2 = 1; d2 < 8; d2 <<= 1) sum += __shfl_xor(sum, d2);
  Ps[wid][ri][c8] = e / sum;
  __syncthreads();

  const int d = lane;
#pragma unroll
  for (int ii = 0; ii < 8; ++ii) {
    float o = 0.f;
#pragma unroll
    for (int j = 0; j < 8; ++j) o += Ps[wid][ii][j] * (float)Vl[wid][j][d];
    outt[((size_t)(ii * 196 + p) * 8 + bb) * 512 + h * 64 + d] = (bf16)o;
  }
}

// ---------------------------------------------------------------------------
extern "C" void kernel_launch(void* const* d_in, const int* in_sizes, int n_in,
                              void* d_out, int out_size, void* d_ws,
                              size_t ws_size, hipStream_t stream) {
  (void)in_sizes; (void)n_in; (void)out_size; (void)ws_size;
  const float* q    = (const float*)d_in[0];
  const float* win  = (const float*)d_in[3];
  const float* bin  = (const float*)d_in[4];
  const float* wout = (const float*)d_in[5];
  const float* bout = (const float*)d_in[6];
  float* out0 = (float*)d_out;
  float* attn = out0 + 6426624L;   // 1569*8*512

  // ws layout (64,749,568 bytes total):
  bf16* qkv  = (bf16*)d_ws;                 // 12544*1536
  bf16* outs = qkv + 19267584L;             // 8*8*196*8*64
  bf16* outt = outs + 6422528L;             // 12544*512
  bf16* wob  = outt + 6422528L;             // 512*512

  // gemm1-only scratch inside attn region of d_out (rewritten by spatial):
  bf16* xb  = (bf16*)attn;                  // 12544*512
  bf16* wqb = xb + 6422528L;                // 1536*512

  prep_kernel<<<7300, 256, 0, stream>>>(q, win, wout, out0, xb, wqb, wob);
  gemm_bt<false><<<dim3(12, 98), 256, 0, stream>>>(xb, wqb, bin, qkv, nullptr,
                                                   1536, 512, 0);
  spatial_attn<<<512, 1024, 0, stream>>>(qkv, attn, outs);
  temporal_attn<<<3136, 256, 0, stream>>>(qkv, outs, outt);
  gemm_bt<true><<<dim3(4, 98), 256, 0, stream>>>(outt, wob, bout, nullptr,
                                                 out0, 512, 512, 4096);
}